// Round 9
// baseline (130.590 us; speedup 1.0000x reference)
//
#include <hip/hip_runtime.h>
#include <math.h>

#define H 4
#define HD 64
#define NN 1024
#define BB 8
#define FIN 256
#define FOUT 256

typedef _Float16 f16x8 __attribute__((ext_vector_type(8)));
typedef _Float16 f16x4 __attribute__((ext_vector_type(4)));
typedef _Float16 f16x2 __attribute__((ext_vector_type(2)));
typedef float f32x4 __attribute__((ext_vector_type(4)));

// ---------------------------------------------------------------------------
// Kernel 0: prep. Blocks 0..1023: pack adj -> 1 bit/edge (streaming).
// Blocks 1024..1039: WT[f][k] = (fp16) W[k][f] in 64x64 tiles.
// (Separate kernel: pack path needs no LDS -> high occupancy; R7 showed
//  grid-fusing it with the 33.8KB-LDS gemm caps it at 4/CU.)
// ---------------------------------------------------------------------------
__global__ __launch_bounds__(256) void prep(const int* __restrict__ adj,
                                            unsigned* __restrict__ adjP,
                                            const float* __restrict__ W,
                                            _Float16* __restrict__ WT) {
  __shared__ float tile[64][68];
  const int tid = threadIdx.x;
  if (blockIdx.x < 1024) {
    size_t widx = (size_t)blockIdx.x * 256 + tid;  // [0, 8*1024*32)
    const int4* p = (const int4*)adj + widx * 8;
    int4 v[8];
#pragma unroll
    for (int i = 0; i < 8; ++i) v[i] = p[i];
    unsigned bits = 0;
#pragma unroll
    for (int i = 0; i < 8; ++i) {
      bits |= (v[i].x != 0 ? 1u : 0u) << (4 * i);
      bits |= (v[i].y != 0 ? 2u : 0u) << (4 * i);
      bits |= (v[i].z != 0 ? 4u : 0u) << (4 * i);
      bits |= (v[i].w != 0 ? 8u : 0u) << (4 * i);
    }
    adjP[widx] = bits;
  } else {
    const int bx = blockIdx.x - 1024;
    const int k0 = (bx & 3) * 64, f0 = (bx >> 2) * 64;
    const int r = tid >> 4, c4 = (tid & 15) * 4;
#pragma unroll
    for (int p = 0; p < 4; ++p) {
      float4 v = *(const float4*)&W[(size_t)(k0 + p * 16 + r) * FOUT + f0 + c4];
      *(float4*)&tile[p * 16 + r][c4] = v;
    }
    __syncthreads();
    const int f = tid >> 2, kg = (tid & 3) * 16;
#pragma unroll
    for (int i = 0; i < 4; ++i) {
      f16x4 o;
#pragma unroll
      for (int j = 0; j < 4; ++j) o[j] = (_Float16)tile[kg + i * 4 + j][f];
      *(f16x4*)&WT[(size_t)(f0 + f) * FIN + k0 + kg + i * 4] = o;
    }
  }
}

// ---------------------------------------------------------------------------
// Kernel 1: h = x @ W via fp16 MFMA. Block = 64 rows x 1 head, 512 blocks.
// Two-phase x staging (16 float4 in flight); W B-frags from WT (L2 b128s).
// Epilogue fuses scores: s1, s2, u=exp(s2), v=exp(0.2*s2).
// ---------------------------------------------------------------------------
__global__ __launch_bounds__(256) void gemm_xw(const float* __restrict__ x,
                                               const _Float16* __restrict__ WT,
                                               const float* __restrict__ a,
                                               _Float16* __restrict__ hT,
                                               float* __restrict__ s1_ws,
                                               float* __restrict__ s2_ws,
                                               float* __restrict__ u_ws,
                                               float* __restrict__ v_ws) {
  __shared__ _Float16 xs[64][264];  // stride 528B
  const int tid = threadIdx.x;
  const int lane = tid & 63, w = tid >> 6;
  const int c = lane & 15, q = lane >> 4;
  const int bn0 = blockIdx.x * 64;
  const int head = blockIdx.y;
  const int b = bn0 >> 10, nb = bn0 & 1023;
  const int bh = b * H + head;

  float4 v[16];
#pragma unroll
  for (int p = 0; p < 16; ++p) {
    int f = p * 256 + tid;  // float4 index in [0, 4096)
    int row = f >> 6, col = (f & 63) * 4;
    v[p] = *(const float4*)&x[(size_t)(bn0 + row) * FIN + col];
  }
#pragma unroll
  for (int p = 0; p < 16; ++p) {
    int f = p * 256 + tid;
    int row = f >> 6, col = (f & 63) * 4;
    f16x4 h4;
    h4[0] = (_Float16)v[p].x; h4[1] = (_Float16)v[p].y;
    h4[2] = (_Float16)v[p].z; h4[3] = (_Float16)v[p].w;
    *(f16x4*)&xs[row][col] = h4;
  }
  __syncthreads();

  f32x4 acc[4];
#pragma unroll
  for (int t = 0; t < 4; ++t) acc[t] = (f32x4){0.f, 0.f, 0.f, 0.f};
  const _Float16* wbase = WT + (size_t)head * 64 * FIN;
#pragma unroll
  for (int ks = 0; ks < 8; ++ks) {
    f16x8 af = *(const f16x8*)&xs[w * 16 + c][ks * 32 + q * 8];
#pragma unroll
    for (int t = 0; t < 4; ++t) {
      f16x8 bf = *(const f16x8*)&wbase[(size_t)(t * 16 + c) * FIN + ks * 32 + q * 8];
      acc[t] = __builtin_amdgcn_mfma_f32_16x16x32_f16(af, bf, acc[t], 0, 0, 0);
    }
  }

  float a1v[4], a2v[4];
#pragma unroll
  for (int t = 0; t < 4; ++t) {
    a1v[t] = a[head * 2 * HD + t * 16 + c];
    a2v[t] = a[head * 2 * HD + HD + t * 16 + c];
  }
  float s1p[4] = {0.f, 0.f, 0.f, 0.f};
  float s2p[4] = {0.f, 0.f, 0.f, 0.f};
#pragma unroll
  for (int t = 0; t < 4; ++t) {
    f16x4 hv;
#pragma unroll
    for (int rr = 0; rr < 4; ++rr) {
      hv[rr] = (_Float16)acc[t][rr];
      s1p[rr] += acc[t][rr] * a1v[t];
      s2p[rr] += acc[t][rr] * a2v[t];
    }
    *(f16x4*)&hT[((size_t)(bh * 64 + t * 16 + c)) * NN + nb + w * 16 + q * 4] = hv;
  }
#pragma unroll
  for (int rr = 0; rr < 4; ++rr) {
    float s1 = s1p[rr], s2 = s2p[rr];
#pragma unroll
    for (int off = 8; off; off >>= 1) {
      s1 += __shfl_xor(s1, off);
      s2 += __shfl_xor(s2, off);
    }
    if (c == 0) {
      int n = nb + w * 16 + q * 4 + rr;
      size_t idx = (size_t)bh * NN + n;
      s1_ws[idx] = s1;
      s2_ws[idx] = s2;
      u_ws[idx] = __expf(s2);
      v_ws[idx] = __expf(0.2f * s2);
    }
  }
}

// ---------------------------------------------------------------------------
// Kernel 2: attention. Block = 16 n-rows x (b,h); 2048 blocks (8/CU), 4 waves.
// R8 core (barrier-free in-register A-fragments, unmasked-max shift) with
// per-lane work HALVED (single row c, acc[4]) and LDS cut 34.3->14.8 KB:
//  - adjT is 16 rows (2 KB)
//  - the epilogue reduction buffer ALIASES the score/adj arrays (dead after
//    the main loop; one extra barrier makes the reuse race-free).
// Expected residency ~5-6 blocks/CU (vs 4) -> cross-block latency hiding.
// ---------------------------------------------------------------------------
__global__ __launch_bounds__(256) void attn(const _Float16* __restrict__ hT,
                                            const float* __restrict__ s1_ws,
                                            const float* __restrict__ s2_ws,
                                            const float* __restrict__ u_ws,
                                            const float* __restrict__ v_ws,
                                            const unsigned* __restrict__ adjP,
                                            float* __restrict__ out) {
  __shared__ float carve[3584];  // 14 KB: s2r|uu|vv|adjT, reused as accbuf
  __shared__ float Mbuf[4];      // block-max exchange
  __shared__ float Lbuf[4][16];  // per-wave row sums
  __shared__ float invLb[16];
  float* s2r = carve;                              // [1024]
  float* uu = carve + 1024;                        // [1024]
  float* vv = carve + 2048;                        // [1024]
  unsigned* adjT = (unsigned*)(carve + 3072);      // [32 words][16 rows]

  const int tid = threadIdx.x, lane = tid & 63, w = tid >> 6;
  const int c = lane & 15, q = lane >> 4;
  const int ntile = blockIdx.x, bh = blockIdx.y;
  const int b = bh >> 2, head = bh & 3;
  const int n0 = ntile * 16;
  const int K0 = w * 256, W0 = w * 8;  // this wave's k-quarter

  float4 s2f;
  {
    size_t base = (size_t)bh * NN + tid * 4;
    s2f = *(const float4*)&s2_ws[base];
    *(float4*)&s2r[tid * 4] = s2f;
    *(float4*)&uu[tid * 4] = *(const float4*)&u_ws[base];
    *(float4*)&vv[tid * 4] = *(const float4*)&v_ws[base];
    if (tid < 128) {  // 16 rows x 32 words
      const int row = tid >> 3, wd0 = (tid & 7) * 4;
      uint4 aw = *(const uint4*)&adjP[((size_t)(b * NN + n0 + row)) * 32 + wd0];
      adjT[(wd0 + 0) * 16 + row] = aw.x;
      adjT[(wd0 + 1) * 16 + row] = aw.y;
      adjT[(wd0 + 2) * 16 + row] = aw.z;
      adjT[(wd0 + 3) * 16 + row] = aw.w;
    }
  }
  // block-wide unmasked max of s2 (register source; normalization cancels
  // any shift >= row max, exact for adj=ones)
  float tmax = fmaxf(fmaxf(s2f.x, s2f.y), fmaxf(s2f.z, s2f.w));
#pragma unroll
  for (int off = 32; off; off >>= 1) tmax = fmaxf(tmax, __shfl_xor(tmax, off));
  if (lane == 0) Mbuf[w] = tmax;
  float s1A = s1_ws[(size_t)bh * NN + n0 + c];  // this lane's row constant
  __syncthreads();  // stage visibility + Mbuf

  float mxall = fmaxf(fmaxf(Mbuf[0], Mbuf[1]), fmaxf(Mbuf[2], Mbuf[3]));
  float tA = s1A + mxall;
  float MA = fmaxf(tA, 0.2f * tA);  // lrelu (monotone => valid shift)
  float ArowA = __expf(s1A - MA), BrowA = __expf(0.2f * s1A - MA), ns1A = -s1A;

  // ---- main loop: barrier-free, in-register A-fragments, k-quarter/wave ----
  float LpA = 0.f;
  f32x4 acc[4];
#pragma unroll
  for (int d = 0; d < 4; ++d) acc[d] = (f32x4){0.f, 0.f, 0.f, 0.f};
  const _Float16* hbase = hT + (size_t)bh * 64 * NN + (size_t)c * NN + K0 + q * 8;

#pragma unroll 2
  for (int ks = 0; ks < 8; ++ks) {
    // B-frags for this k-slice, all 4 d-blocks (issued before A-build -> the
    // P-gen VALU below hides the L2 latency)
    f16x8 bf0 = *(const f16x8*)(hbase + (size_t)0 * 16 * NN + ks * 32);
    f16x8 bf1 = *(const f16x8*)(hbase + (size_t)1 * 16 * NN + ks * 32);
    f16x8 bf2 = *(const f16x8*)(hbase + (size_t)2 * 16 * NN + ks * 32);
    f16x8 bf3 = *(const f16x8*)(hbase + (size_t)3 * 16 * NN + ks * 32);

    int m0 = K0 + ks * 32 + q * 8;
    f32x4 sa = *(const f32x4*)&s2r[m0];
    f32x4 sb = *(const f32x4*)&s2r[m0 + 4];
    f32x4 ua = *(const f32x4*)&uu[m0];
    f32x4 ub = *(const f32x4*)&uu[m0 + 4];
    f32x4 va = *(const f32x4*)&vv[m0];
    f32x4 vb = *(const f32x4*)&vv[m0 + 4];
    unsigned wdA = adjT[(W0 + ks) * 16 + c] >> (q * 8);

    float pA[8];
#pragma unroll
    for (int j = 0; j < 4; ++j) {
      float a0 = (sa[j] >= ns1A) ? ArowA * ua[j] : BrowA * va[j];
      float a1 = (sb[j] >= ns1A) ? ArowA * ub[j] : BrowA * vb[j];
      pA[j] = ((wdA >> j) & 1u) ? a0 : 0.f;
      pA[j + 4] = ((wdA >> (j + 4)) & 1u) ? a1 : 0.f;
    }
    LpA += ((pA[0] + pA[1]) + (pA[2] + pA[3])) + ((pA[4] + pA[5]) + (pA[6] + pA[7]));

    union { f16x8 v8; f16x2 h2[4]; } PA;
#pragma unroll
    for (int j = 0; j < 4; ++j)
      PA.h2[j] = __builtin_bit_cast(f16x2, __builtin_amdgcn_cvt_pkrtz(pA[2 * j], pA[2 * j + 1]));

    acc[0] = __builtin_amdgcn_mfma_f32_16x16x32_f16(PA.v8, bf0, acc[0], 0, 0, 0);
    acc[1] = __builtin_amdgcn_mfma_f32_16x16x32_f16(PA.v8, bf1, acc[1], 0, 0, 0);
    acc[2] = __builtin_amdgcn_mfma_f32_16x16x32_f16(PA.v8, bf2, acc[2], 0, 0, 0);
    acc[3] = __builtin_amdgcn_mfma_f32_16x16x32_f16(PA.v8, bf3, acc[3], 0, 0, 0);
  }

  // ---- epilogue: L + acc cross-wave k-reduction, accbuf ALIASED on carve ---
  LpA += __shfl_xor(LpA, 16);
  LpA += __shfl_xor(LpA, 32);
  if (lane < 16) Lbuf[w][c] = LpA;
  __syncthreads();  // A: carve (scores/adj) now dead everywhere; Lbuf visible

  // accbuf layout on carve: [(pub 0..1)*4 + d][lane] of f32x4 = 2048 floats
  if (w >= 2) {  // round 1: waves 2,3 publish
#pragma unroll
    for (int d = 0; d < 4; ++d)
      *(f32x4*)&carve[(((w - 2) * 4 + d) << 8) + (lane << 2)] = acc[d];
  }
  if (tid < 16) {
    invLb[tid] = 1.0f / (Lbuf[0][tid] + Lbuf[1][tid] + Lbuf[2][tid] + Lbuf[3][tid]);
  }
  __syncthreads();  // B
  if (w < 2) {
#pragma unroll
    for (int d = 0; d < 4; ++d)
      acc[d] += *(const f32x4*)&carve[((w * 4 + d) << 8) + (lane << 2)];
  }
  __syncthreads();  // C: region 0 reads done before rewrite
  if (w == 1) {  // round 2: wave 1 publishes into region 0
#pragma unroll
    for (int d = 0; d < 4; ++d)
      *(f32x4*)&carve[(d << 8) + (lane << 2)] = acc[d];
  }
  __syncthreads();  // D
  if (w == 0) {
#pragma unroll
    for (int d = 0; d < 4; ++d)
      acc[d] += *(const f32x4*)&carve[(d << 8) + (lane << 2)];
#pragma unroll
    for (int rr = 0; rr < 4; ++rr) {
      int nloc = q * 4 + rr;
      float il = invLb[nloc];
      size_t o = ((size_t)(b * NN + n0 + nloc)) * FOUT + head * 64;
#pragma unroll
      for (int d = 0; d < 4; ++d) out[o + d * 16 + c] = acc[d][rr] * il;
    }
  }
}

extern "C" void kernel_launch(void* const* d_in, const int* in_sizes, int n_in,
                              void* d_out, int out_size, void* d_ws, size_t ws_size,
                              hipStream_t stream) {
  const float* x = (const float*)d_in[0];
  const int* adj = (const int*)d_in[1];
  const float* W = (const float*)d_in[2];
  const float* a = (const float*)d_in[3];
  float* out = (float*)d_out;

  char* ws = (char*)d_ws;
  _Float16* hT = (_Float16*)ws;                              // 4 MB
  _Float16* WT = (_Float16*)(ws + (size_t)4 * 1024 * 1024);  // 128 KB
  float* s1_ws = (float*)(ws + (size_t)4 * 1024 * 1024 + 128 * 1024);
  float* s2_ws = s1_ws + (size_t)BB * H * NN;
  float* u_ws = s2_ws + (size_t)BB * H * NN;
  float* v_ws = u_ws + (size_t)BB * H * NN;
  unsigned* adjP = (unsigned*)(v_ws + (size_t)BB * H * NN);  // 1 MB

  prep<<<1040, 256, 0, stream>>>(adj, adjP, W, WT);
  gemm_xw<<<dim3(128, 4), 256, 0, stream>>>(x, WT, a, hT, s1_ws, s2_ws, u_ws, v_ws);
  attn<<<dim3(64, 32), 256, 0, stream>>>(hT, s1_ws, s2_ws, u_ws, v_ws, adjP, out);
}

// Round 10
// 117.842 us; speedup vs baseline: 1.1082x; 1.1082x over previous
//
#include <hip/hip_runtime.h>
#include <math.h>

#define H 4
#define HD 64
#define NN 1024
#define BB 8
#define FIN 256
#define FOUT 256

typedef _Float16 f16x8 __attribute__((ext_vector_type(8)));
typedef _Float16 f16x4 __attribute__((ext_vector_type(4)));
typedef _Float16 f16x2 __attribute__((ext_vector_type(2)));
typedef float f32x4 __attribute__((ext_vector_type(4)));

// ---------------------------------------------------------------------------
// Kernel 0: WT[f][k] = (fp16) W[k][f] in 64x64 tiles. 16 blocks (~2us).
// ---------------------------------------------------------------------------
__global__ __launch_bounds__(256) void prep_w(const float* __restrict__ W,
                                              _Float16* __restrict__ WT) {
  __shared__ float tile[64][68];
  const int tid = threadIdx.x;
  const int bx = blockIdx.x;
  const int k0 = (bx & 3) * 64, f0 = (bx >> 2) * 64;
  const int r = tid >> 4, c4 = (tid & 15) * 4;
#pragma unroll
  for (int p = 0; p < 4; ++p) {
    float4 v = *(const float4*)&W[(size_t)(k0 + p * 16 + r) * FOUT + f0 + c4];
    *(float4*)&tile[p * 16 + r][c4] = v;
  }
  __syncthreads();
  const int f = tid >> 2, kg = (tid & 3) * 16;
#pragma unroll
  for (int i = 0; i < 4; ++i) {
    f16x4 o;
#pragma unroll
    for (int j = 0; j < 4; ++j) o[j] = (_Float16)tile[kg + i * 4 + j][f];
    *(f16x4*)&WT[(size_t)(f0 + f) * FIN + k0 + kg + i * 4] = o;
  }
}

// ---------------------------------------------------------------------------
// Kernel 1: fused, ZERO static LDS (fixes R7's flaw: pack blocks no longer
// inherit a 33.8KB LDS reservation).
// bx < 128: h = x @ W via fp16 MFMA, A-frags read directly from global x
// (each x element read exactly once per block — R1-verified path).
// bx >= 128: adj bit-pack (1024 block-equivalents, overlapped with GEMM).
// GEMM epilogue fuses scores: s1, s2, u=exp(s2), v=exp(0.2*s2).
// ---------------------------------------------------------------------------
__global__ __launch_bounds__(256) void gemm_pack(const float* __restrict__ x,
                                                 const _Float16* __restrict__ WT,
                                                 const float* __restrict__ a,
                                                 const int* __restrict__ adj,
                                                 unsigned* __restrict__ adjP,
                                                 _Float16* __restrict__ hT,
                                                 float* __restrict__ s1_ws,
                                                 float* __restrict__ s2_ws,
                                                 float* __restrict__ u_ws,
                                                 float* __restrict__ v_ws) {
  const int tid = threadIdx.x;

  if (blockIdx.x >= 128) {  // ---- adj pack path (no LDS, high occupancy) ----
    const int p = (blockIdx.x - 128) + 256 * blockIdx.y;  // 0..1023
    size_t widx = (size_t)p * 256 + tid;                  // [0, 8*1024*32)
    const int4* ap = (const int4*)adj + widx * 8;
    int4 v[8];
#pragma unroll
    for (int i = 0; i < 8; ++i) v[i] = ap[i];
    unsigned bits = 0;
#pragma unroll
    for (int i = 0; i < 8; ++i) {
      bits |= (v[i].x != 0 ? 1u : 0u) << (4 * i);
      bits |= (v[i].y != 0 ? 2u : 0u) << (4 * i);
      bits |= (v[i].z != 0 ? 4u : 0u) << (4 * i);
      bits |= (v[i].w != 0 ? 8u : 0u) << (4 * i);
    }
    adjP[widx] = bits;
    return;
  }

  // ---- GEMM path (LDS-free) ----
  const int lane = tid & 63, w = tid >> 6;
  const int c = lane & 15, q = lane >> 4;
  const int bn0 = blockIdx.x * 64;
  const int head = blockIdx.y;
  const int b = bn0 >> 10, nb = bn0 & 1023;
  const int bh = b * H + head;

  const _Float16* wbase = WT + (size_t)head * 64 * FIN;
  const float* xrow = x + (size_t)(bn0 + w * 16 + c) * FIN;

  // Issue all 16 x loads up front (latency hidden under the MFMA chain).
  float4 xa[16];
#pragma unroll
  for (int ks = 0; ks < 8; ++ks) {
    xa[2 * ks] = *(const float4*)&xrow[ks * 32 + q * 8];
    xa[2 * ks + 1] = *(const float4*)&xrow[ks * 32 + q * 8 + 4];
  }

  f32x4 acc[4];
#pragma unroll
  for (int t = 0; t < 4; ++t) acc[t] = (f32x4){0.f, 0.f, 0.f, 0.f};

#pragma unroll
  for (int ks = 0; ks < 8; ++ks) {
    float4 u0 = xa[2 * ks], u1 = xa[2 * ks + 1];
    f16x8 af;
    af[0] = (_Float16)u0.x; af[1] = (_Float16)u0.y;
    af[2] = (_Float16)u0.z; af[3] = (_Float16)u0.w;
    af[4] = (_Float16)u1.x; af[5] = (_Float16)u1.y;
    af[6] = (_Float16)u1.z; af[7] = (_Float16)u1.w;
#pragma unroll
    for (int t = 0; t < 4; ++t) {
      f16x8 bf = *(const f16x8*)&wbase[(size_t)(t * 16 + c) * FIN + ks * 32 + q * 8];
      acc[t] = __builtin_amdgcn_mfma_f32_16x16x32_f16(af, bf, acc[t], 0, 0, 0);
    }
  }

  float a1v[4], a2v[4];
#pragma unroll
  for (int t = 0; t < 4; ++t) {
    a1v[t] = a[head * 2 * HD + t * 16 + c];
    a2v[t] = a[head * 2 * HD + HD + t * 16 + c];
  }
  float s1p[4] = {0.f, 0.f, 0.f, 0.f};
  float s2p[4] = {0.f, 0.f, 0.f, 0.f};
#pragma unroll
  for (int t = 0; t < 4; ++t) {
    f16x4 hv;
#pragma unroll
    for (int rr = 0; rr < 4; ++rr) {
      hv[rr] = (_Float16)acc[t][rr];
      s1p[rr] += acc[t][rr] * a1v[t];
      s2p[rr] += acc[t][rr] * a2v[t];
    }
    *(f16x4*)&hT[((size_t)(bh * 64 + t * 16 + c)) * NN + nb + w * 16 + q * 4] = hv;
  }
#pragma unroll
  for (int rr = 0; rr < 4; ++rr) {
    float s1 = s1p[rr], s2 = s2p[rr];
#pragma unroll
    for (int off = 8; off; off >>= 1) {
      s1 += __shfl_xor(s1, off);
      s2 += __shfl_xor(s2, off);
    }
    if (c == 0) {
      int n = nb + w * 16 + q * 4 + rr;
      size_t idx = (size_t)bh * NN + n;
      s1_ws[idx] = s1;
      s2_ws[idx] = s2;
      u_ws[idx] = __expf(s2);
      v_ws[idx] = __expf(0.2f * s2);
    }
  }
}

// ---------------------------------------------------------------------------
// Kernel 2: attention. Block = 32 n-rows x (b,h); 1024 blocks, 4 waves.
// BYTE-IDENTICAL to the 114.5us round-8 version (R9's 16-row split regressed:
// per-block stage+epilogue is the fixed cost — fewer, larger blocks win).
// Barrier-free in-register A-fragments; unmasked block-max shift (softmax
// normalization cancels any shift >= row max; exact for adj=ones).
// ---------------------------------------------------------------------------
__global__ __launch_bounds__(256) void attn(const _Float16* __restrict__ hT,
                                            const float* __restrict__ s1_ws,
                                            const float* __restrict__ s2_ws,
                                            const float* __restrict__ u_ws,
                                            const float* __restrict__ v_ws,
                                            const unsigned* __restrict__ adjP,
                                            float* __restrict__ out) {
  __shared__ float s2r[NN], uu[NN], vv[NN];   // 12 KB
  __shared__ unsigned adjT[32][32];           // 4 KB, [word][row]
  __shared__ float accbuf[2][2][4][64][4];    // 16 KB reduction buffer
  __shared__ float Mbuf[4];                   // 16 B (block max exchange)
  __shared__ float Lbuf[4][32];               // 512 B
  __shared__ float invLb[32];                 // 128 B
  const int tid = threadIdx.x, lane = tid & 63, w = tid >> 6;
  const int c = lane & 15, q = lane >> 4;
  const int ntile = blockIdx.x, bh = blockIdx.y;
  const int b = bh >> 2, head = bh & 3;
  const int n0 = ntile * 32;
  const int K0 = w * 256, W0 = w * 8;  // this wave's k-quarter

  float4 s2f;
  {
    size_t base = (size_t)bh * NN + tid * 4;
    s2f = *(const float4*)&s2_ws[base];
    *(float4*)&s2r[tid * 4] = s2f;
    *(float4*)&uu[tid * 4] = *(const float4*)&u_ws[base];
    *(float4*)&vv[tid * 4] = *(const float4*)&v_ws[base];
    const int row = tid >> 3, wd0 = (tid & 7) * 4;
    uint4 aw = *(const uint4*)&adjP[((size_t)(b * NN + n0 + row)) * 32 + wd0];
    adjT[wd0 + 0][row] = aw.x;
    adjT[wd0 + 1][row] = aw.y;
    adjT[wd0 + 2][row] = aw.z;
    adjT[wd0 + 3][row] = aw.w;
  }
  // block-wide unmasked max of s2 (register source, no LDS dependency)
  float tmax = fmaxf(fmaxf(s2f.x, s2f.y), fmaxf(s2f.z, s2f.w));
#pragma unroll
  for (int off = 32; off; off >>= 1) tmax = fmaxf(tmax, __shfl_xor(tmax, off));
  if (lane == 0) Mbuf[w] = tmax;
  float s1A = s1_ws[(size_t)bh * NN + n0 + c];       // row c
  float s1B = s1_ws[(size_t)bh * NN + n0 + 16 + c];  // row c+16
  __syncthreads();  // stage visibility + Mbuf

  float mxall = fmaxf(fmaxf(Mbuf[0], Mbuf[1]), fmaxf(Mbuf[2], Mbuf[3]));
  float tA = s1A + mxall, tB = s1B + mxall;
  float MA = fmaxf(tA, 0.2f * tA);  // lrelu (monotone => valid shift)
  float MB = fmaxf(tB, 0.2f * tB);
  float ArowA = __expf(s1A - MA), BrowA = __expf(0.2f * s1A - MA), ns1A = -s1A;
  float ArowB = __expf(s1B - MB), BrowB = __expf(0.2f * s1B - MB), ns1B = -s1B;

  // ---- main loop: barrier-free, in-register A-fragments, k-quarter/wave ----
  float LpA = 0.f, LpB = 0.f;
  f32x4 acc[2][4];
#pragma unroll
  for (int t = 0; t < 2; ++t)
#pragma unroll
    for (int d = 0; d < 4; ++d) acc[t][d] = (f32x4){0.f, 0.f, 0.f, 0.f};
  const _Float16* hbase = hT + (size_t)bh * 64 * NN + (size_t)c * NN + K0 + q * 8;

#pragma unroll 2
  for (int ks = 0; ks < 8; ++ks) {
    // B-frags for this k-slice, all 4 d-blocks (issued before A-build -> the
    // ~160cy of P-gen VALU below hides the L2 latency)
    f16x8 bf0 = *(const f16x8*)(hbase + (size_t)0 * 16 * NN + ks * 32);
    f16x8 bf1 = *(const f16x8*)(hbase + (size_t)1 * 16 * NN + ks * 32);
    f16x8 bf2 = *(const f16x8*)(hbase + (size_t)2 * 16 * NN + ks * 32);
    f16x8 bf3 = *(const f16x8*)(hbase + (size_t)3 * 16 * NN + ks * 32);

    int m0 = K0 + ks * 32 + q * 8;
    f32x4 sa = *(const f32x4*)&s2r[m0];
    f32x4 sb = *(const f32x4*)&s2r[m0 + 4];
    f32x4 ua = *(const f32x4*)&uu[m0];
    f32x4 ub = *(const f32x4*)&uu[m0 + 4];
    f32x4 va = *(const f32x4*)&vv[m0];
    f32x4 vb = *(const f32x4*)&vv[m0 + 4];
    unsigned wdA = adjT[W0 + ks][c] >> (q * 8);
    unsigned wdB = adjT[W0 + ks][c + 16] >> (q * 8);

    float pA[8], pB[8];
#pragma unroll
    for (int j = 0; j < 4; ++j) {
      float a0 = (sa[j] >= ns1A) ? ArowA * ua[j] : BrowA * va[j];
      float a1 = (sb[j] >= ns1A) ? ArowA * ub[j] : BrowA * vb[j];
      pA[j] = ((wdA >> j) & 1u) ? a0 : 0.f;
      pA[j + 4] = ((wdA >> (j + 4)) & 1u) ? a1 : 0.f;
      float b0 = (sa[j] >= ns1B) ? ArowB * ua[j] : BrowB * va[j];
      float b1 = (sb[j] >= ns1B) ? ArowB * ub[j] : BrowB * vb[j];
      pB[j] = ((wdB >> j) & 1u) ? b0 : 0.f;
      pB[j + 4] = ((wdB >> (j + 4)) & 1u) ? b1 : 0.f;
    }
    LpA += ((pA[0] + pA[1]) + (pA[2] + pA[3])) + ((pA[4] + pA[5]) + (pA[6] + pA[7]));
    LpB += ((pB[0] + pB[1]) + (pB[2] + pB[3])) + ((pB[4] + pB[5]) + (pB[6] + pB[7]));

    union { f16x8 v8; f16x2 h2[4]; } PA, PB;
#pragma unroll
    for (int j = 0; j < 4; ++j) {
      PA.h2[j] = __builtin_bit_cast(f16x2, __builtin_amdgcn_cvt_pkrtz(pA[2 * j], pA[2 * j + 1]));
      PB.h2[j] = __builtin_bit_cast(f16x2, __builtin_amdgcn_cvt_pkrtz(pB[2 * j], pB[2 * j + 1]));
    }

    acc[0][0] = __builtin_amdgcn_mfma_f32_16x16x32_f16(PA.v8, bf0, acc[0][0], 0, 0, 0);
    acc[0][1] = __builtin_amdgcn_mfma_f32_16x16x32_f16(PA.v8, bf1, acc[0][1], 0, 0, 0);
    acc[0][2] = __builtin_amdgcn_mfma_f32_16x16x32_f16(PA.v8, bf2, acc[0][2], 0, 0, 0);
    acc[0][3] = __builtin_amdgcn_mfma_f32_16x16x32_f16(PA.v8, bf3, acc[0][3], 0, 0, 0);
    acc[1][0] = __builtin_amdgcn_mfma_f32_16x16x32_f16(PB.v8, bf0, acc[1][0], 0, 0, 0);
    acc[1][1] = __builtin_amdgcn_mfma_f32_16x16x32_f16(PB.v8, bf1, acc[1][1], 0, 0, 0);
    acc[1][2] = __builtin_amdgcn_mfma_f32_16x16x32_f16(PB.v8, bf2, acc[1][2], 0, 0, 0);
    acc[1][3] = __builtin_amdgcn_mfma_f32_16x16x32_f16(PB.v8, bf3, acc[1][3], 0, 0, 0);
  }

  // ---- epilogue: L + acc cross-wave k-reduction (2-round butterfly) ----
  LpA += __shfl_xor(LpA, 16);
  LpA += __shfl_xor(LpA, 32);
  LpB += __shfl_xor(LpB, 16);
  LpB += __shfl_xor(LpB, 32);
  if (lane < 16) {
    Lbuf[w][c] = LpA;
    Lbuf[w][16 + c] = LpB;
  }
  if (w >= 2) {  // round 1: waves 2,3 publish
#pragma unroll
    for (int t = 0; t < 2; ++t)
#pragma unroll
      for (int d = 0; d < 4; ++d)
        *(f32x4*)&accbuf[w - 2][t][d][lane][0] = acc[t][d];
  }
  __syncthreads();
  if (w < 2) {
#pragma unroll
    for (int t = 0; t < 2; ++t)
#pragma unroll
      for (int d = 0; d < 4; ++d)
        acc[t][d] += *(const f32x4*)&accbuf[w][t][d][lane][0];
  }
  if (tid < 32) {
    float Ls = Lbuf[0][tid] + Lbuf[1][tid] + Lbuf[2][tid] + Lbuf[3][tid];
    invLb[tid] = 1.0f / Ls;
  }
  __syncthreads();
  if (w == 1) {  // round 2: wave 1 publishes
#pragma unroll
    for (int t = 0; t < 2; ++t)
#pragma unroll
      for (int d = 0; d < 4; ++d)
        *(f32x4*)&accbuf[0][t][d][lane][0] = acc[t][d];
  }
  __syncthreads();
  if (w == 0) {
#pragma unroll
    for (int t = 0; t < 2; ++t) {
#pragma unroll
      for (int d = 0; d < 4; ++d)
        acc[t][d] += *(const f32x4*)&accbuf[0][t][d][lane][0];
#pragma unroll
      for (int rr = 0; rr < 4; ++rr) {
        int nloc = t * 16 + q * 4 + rr;
        float il = invLb[nloc];
        size_t o = ((size_t)(b * NN + n0 + nloc)) * FOUT + head * 64;
#pragma unroll
        for (int d = 0; d < 4; ++d) out[o + d * 16 + c] = acc[t][d][rr] * il;
      }
    }
  }
}

extern "C" void kernel_launch(void* const* d_in, const int* in_sizes, int n_in,
                              void* d_out, int out_size, void* d_ws, size_t ws_size,
                              hipStream_t stream) {
  const float* x = (const float*)d_in[0];
  const int* adj = (const int*)d_in[1];
  const float* W = (const float*)d_in[2];
  const float* a = (const float*)d_in[3];
  float* out = (float*)d_out;

  char* ws = (char*)d_ws;
  _Float16* hT = (_Float16*)ws;                              // 4 MB
  _Float16* WT = (_Float16*)(ws + (size_t)4 * 1024 * 1024);  // 128 KB
  float* s1_ws = (float*)(ws + (size_t)4 * 1024 * 1024 + 128 * 1024);
  float* s2_ws = s1_ws + (size_t)BB * H * NN;
  float* u_ws = s2_ws + (size_t)BB * H * NN;
  float* v_ws = u_ws + (size_t)BB * H * NN;
  unsigned* adjP = (unsigned*)(v_ws + (size_t)BB * H * NN);  // 1 MB

  prep_w<<<16, 256, 0, stream>>>(W, WT);
  gemm_pack<<<dim3(384, 4), 256, 0, stream>>>(x, WT, a, adj, adjP, hT, s1_ws, s2_ws,
                                              u_ws, v_ws);
  attn<<<dim3(32, 32), 256, 0, stream>>>(hT, s1_ws, s2_ws, u_ws, v_ws, adjP, out);
}

// Round 11
// 116.996 us; speedup vs baseline: 1.1162x; 1.0072x over previous
//
#include <hip/hip_runtime.h>
#include <math.h>

#define H 4
#define HD 64
#define NN 1024
#define BB 8
#define FIN 256
#define FOUT 256

typedef _Float16 f16x8 __attribute__((ext_vector_type(8)));
typedef _Float16 f16x4 __attribute__((ext_vector_type(4)));
typedef _Float16 f16x2 __attribute__((ext_vector_type(2)));
typedef float f32x4 __attribute__((ext_vector_type(4)));

// ---------------------------------------------------------------------------
// Kernel 0: prep. Blocks 0..1023: pack adj -> 1 bit/edge (streaming).
// Blocks 1024..1039: WT[f][k] = (fp16) W[k][f] in 64x64 tiles.
// (Pack and WT overlap inside this one kernel; R7/R10 showed fusing pack
//  into gemm's grid regresses.)
// ---------------------------------------------------------------------------
__global__ __launch_bounds__(256) void prep(const int* __restrict__ adj,
                                            unsigned* __restrict__ adjP,
                                            const float* __restrict__ W,
                                            _Float16* __restrict__ WT) {
  __shared__ float tile[64][68];
  const int tid = threadIdx.x;
  if (blockIdx.x < 1024) {
    size_t widx = (size_t)blockIdx.x * 256 + tid;  // [0, 8*1024*32)
    const int4* p = (const int4*)adj + widx * 8;
    int4 v[8];
#pragma unroll
    for (int i = 0; i < 8; ++i) v[i] = p[i];
    unsigned bits = 0;
#pragma unroll
    for (int i = 0; i < 8; ++i) {
      bits |= (v[i].x != 0 ? 1u : 0u) << (4 * i);
      bits |= (v[i].y != 0 ? 2u : 0u) << (4 * i);
      bits |= (v[i].z != 0 ? 4u : 0u) << (4 * i);
      bits |= (v[i].w != 0 ? 8u : 0u) << (4 * i);
    }
    adjP[widx] = bits;
  } else {
    const int bx = blockIdx.x - 1024;
    const int k0 = (bx & 3) * 64, f0 = (bx >> 2) * 64;
    const int r = tid >> 4, c4 = (tid & 15) * 4;
#pragma unroll
    for (int p = 0; p < 4; ++p) {
      float4 v = *(const float4*)&W[(size_t)(k0 + p * 16 + r) * FOUT + f0 + c4];
      *(float4*)&tile[p * 16 + r][c4] = v;
    }
    __syncthreads();
    const int f = tid >> 2, kg = (tid & 3) * 16;
#pragma unroll
    for (int i = 0; i < 4; ++i) {
      f16x4 o;
#pragma unroll
      for (int j = 0; j < 4; ++j) o[j] = (_Float16)tile[kg + i * 4 + j][f];
      *(f16x4*)&WT[(size_t)(f0 + f) * FIN + k0 + kg + i * 4] = o;
    }
  }
}

// ---------------------------------------------------------------------------
// Kernel 1: h = x @ W via fp16 MFMA. Block = 64 rows x 1 head, 512 blocks.
// Two-phase x staging (16 float4 in flight); W B-frags from WT (L2 b128s).
// Epilogue fuses scores: s1, s2, u=exp(s2), v=exp(0.2*s2).
// (R10 showed the LDS-free variant regresses; keep the staged version.)
// ---------------------------------------------------------------------------
__global__ __launch_bounds__(256) void gemm_xw(const float* __restrict__ x,
                                               const _Float16* __restrict__ WT,
                                               const float* __restrict__ a,
                                               _Float16* __restrict__ hT,
                                               float* __restrict__ s1_ws,
                                               float* __restrict__ s2_ws,
                                               float* __restrict__ u_ws,
                                               float* __restrict__ v_ws) {
  __shared__ _Float16 xs[64][264];  // stride 528B
  const int tid = threadIdx.x;
  const int lane = tid & 63, w = tid >> 6;
  const int c = lane & 15, q = lane >> 4;
  const int bn0 = blockIdx.x * 64;
  const int head = blockIdx.y;
  const int b = bn0 >> 10, nb = bn0 & 1023;
  const int bh = b * H + head;

  float4 v[16];
#pragma unroll
  for (int p = 0; p < 16; ++p) {
    int f = p * 256 + tid;  // float4 index in [0, 4096)
    int row = f >> 6, col = (f & 63) * 4;
    v[p] = *(const float4*)&x[(size_t)(bn0 + row) * FIN + col];
  }
#pragma unroll
  for (int p = 0; p < 16; ++p) {
    int f = p * 256 + tid;
    int row = f >> 6, col = (f & 63) * 4;
    f16x4 h4;
    h4[0] = (_Float16)v[p].x; h4[1] = (_Float16)v[p].y;
    h4[2] = (_Float16)v[p].z; h4[3] = (_Float16)v[p].w;
    *(f16x4*)&xs[row][col] = h4;
  }
  __syncthreads();

  f32x4 acc[4];
#pragma unroll
  for (int t = 0; t < 4; ++t) acc[t] = (f32x4){0.f, 0.f, 0.f, 0.f};
  const _Float16* wbase = WT + (size_t)head * 64 * FIN;
#pragma unroll
  for (int ks = 0; ks < 8; ++ks) {
    f16x8 af = *(const f16x8*)&xs[w * 16 + c][ks * 32 + q * 8];
#pragma unroll
    for (int t = 0; t < 4; ++t) {
      f16x8 bf = *(const f16x8*)&wbase[(size_t)(t * 16 + c) * FIN + ks * 32 + q * 8];
      acc[t] = __builtin_amdgcn_mfma_f32_16x16x32_f16(af, bf, acc[t], 0, 0, 0);
    }
  }

  float a1v[4], a2v[4];
#pragma unroll
  for (int t = 0; t < 4; ++t) {
    a1v[t] = a[head * 2 * HD + t * 16 + c];
    a2v[t] = a[head * 2 * HD + HD + t * 16 + c];
  }
  float s1p[4] = {0.f, 0.f, 0.f, 0.f};
  float s2p[4] = {0.f, 0.f, 0.f, 0.f};
#pragma unroll
  for (int t = 0; t < 4; ++t) {
    f16x4 hv;
#pragma unroll
    for (int rr = 0; rr < 4; ++rr) {
      hv[rr] = (_Float16)acc[t][rr];
      s1p[rr] += acc[t][rr] * a1v[t];
      s2p[rr] += acc[t][rr] * a2v[t];
    }
    *(f16x4*)&hT[((size_t)(bh * 64 + t * 16 + c)) * NN + nb + w * 16 + q * 4] = hv;
  }
#pragma unroll
  for (int rr = 0; rr < 4; ++rr) {
    float s1 = s1p[rr], s2 = s2p[rr];
#pragma unroll
    for (int off = 8; off; off >>= 1) {
      s1 += __shfl_xor(s1, off);
      s2 += __shfl_xor(s2, off);
    }
    if (c == 0) {
      int n = nb + w * 16 + q * 4 + rr;
      size_t idx = (size_t)bh * NN + n;
      s1_ws[idx] = s1;
      s2_ws[idx] = s2;
      u_ws[idx] = __expf(s2);
      v_ws[idx] = __expf(0.2f * s2);
    }
  }
}

// ---------------------------------------------------------------------------
// Kernel 2: attention. Block = 32 n-rows x (b,h); 1024 blocks, 4 waves.
// R8's 114.5us kernel with ONE change: bijective XCD-aware block swizzle
// (1024%8==0) so all 32 ntiles of a bh (sharing the same 128KB hT slice +
// score rows + adjP rows) land on one XCD's L2 instead of being replicated
// into all 8 L2s.
// Barrier-free in-register A-fragments; unmasked block-max shift (softmax
// normalization cancels any shift >= row max; exact for adj=ones).
// ---------------------------------------------------------------------------
__global__ __launch_bounds__(256) void attn(const _Float16* __restrict__ hT,
                                            const float* __restrict__ s1_ws,
                                            const float* __restrict__ s2_ws,
                                            const float* __restrict__ u_ws,
                                            const float* __restrict__ v_ws,
                                            const unsigned* __restrict__ adjP,
                                            float* __restrict__ out) {
  __shared__ float s2r[NN], uu[NN], vv[NN];   // 12 KB
  __shared__ unsigned adjT[32][32];           // 4 KB, [word][row]
  __shared__ float accbuf[2][2][4][64][4];    // 16 KB reduction buffer
  __shared__ float Mbuf[4];                   // 16 B (block max exchange)
  __shared__ float Lbuf[4][32];               // 512 B
  __shared__ float invLb[32];                 // 128 B
  const int tid = threadIdx.x, lane = tid & 63, w = tid >> 6;
  const int c = lane & 15, q = lane >> 4;
  // XCD swizzle: linear id -> (xcd, slot); each XCD gets 4 contiguous bh
  // groups (128 consecutive work items). Bijective since 1024 % 8 == 0.
  const int bid = blockIdx.y * 32 + blockIdx.x;
  const int work = ((bid & 7) << 7) | (bid >> 3);
  const int ntile = work & 31, bh = work >> 5;
  const int b = bh >> 2, head = bh & 3;
  const int n0 = ntile * 32;
  const int K0 = w * 256, W0 = w * 8;  // this wave's k-quarter

  float4 s2f;
  {
    size_t base = (size_t)bh * NN + tid * 4;
    s2f = *(const float4*)&s2_ws[base];
    *(float4*)&s2r[tid * 4] = s2f;
    *(float4*)&uu[tid * 4] = *(const float4*)&u_ws[base];
    *(float4*)&vv[tid * 4] = *(const float4*)&v_ws[base];
    const int row = tid >> 3, wd0 = (tid & 7) * 4;
    uint4 aw = *(const uint4*)&adjP[((size_t)(b * NN + n0 + row)) * 32 + wd0];
    adjT[wd0 + 0][row] = aw.x;
    adjT[wd0 + 1][row] = aw.y;
    adjT[wd0 + 2][row] = aw.z;
    adjT[wd0 + 3][row] = aw.w;
  }
  // block-wide unmasked max of s2 (register source, no LDS dependency)
  float tmax = fmaxf(fmaxf(s2f.x, s2f.y), fmaxf(s2f.z, s2f.w));
#pragma unroll
  for (int off = 32; off; off >>= 1) tmax = fmaxf(tmax, __shfl_xor(tmax, off));
  if (lane == 0) Mbuf[w] = tmax;
  float s1A = s1_ws[(size_t)bh * NN + n0 + c];       // row c
  float s1B = s1_ws[(size_t)bh * NN + n0 + 16 + c];  // row c+16
  __syncthreads();  // stage visibility + Mbuf

  float mxall = fmaxf(fmaxf(Mbuf[0], Mbuf[1]), fmaxf(Mbuf[2], Mbuf[3]));
  float tA = s1A + mxall, tB = s1B + mxall;
  float MA = fmaxf(tA, 0.2f * tA);  // lrelu (monotone => valid shift)
  float MB = fmaxf(tB, 0.2f * tB);
  float ArowA = __expf(s1A - MA), BrowA = __expf(0.2f * s1A - MA), ns1A = -s1A;
  float ArowB = __expf(s1B - MB), BrowB = __expf(0.2f * s1B - MB), ns1B = -s1B;

  // ---- main loop: barrier-free, in-register A-fragments, k-quarter/wave ----
  float LpA = 0.f, LpB = 0.f;
  f32x4 acc[2][4];
#pragma unroll
  for (int t = 0; t < 2; ++t)
#pragma unroll
    for (int d = 0; d < 4; ++d) acc[t][d] = (f32x4){0.f, 0.f, 0.f, 0.f};
  const _Float16* hbase = hT + (size_t)bh * 64 * NN + (size_t)c * NN + K0 + q * 8;

#pragma unroll 2
  for (int ks = 0; ks < 8; ++ks) {
    // B-frags for this k-slice, all 4 d-blocks (issued before A-build -> the
    // ~160cy of P-gen VALU below hides the L2 latency)
    f16x8 bf0 = *(const f16x8*)(hbase + (size_t)0 * 16 * NN + ks * 32);
    f16x8 bf1 = *(const f16x8*)(hbase + (size_t)1 * 16 * NN + ks * 32);
    f16x8 bf2 = *(const f16x8*)(hbase + (size_t)2 * 16 * NN + ks * 32);
    f16x8 bf3 = *(const f16x8*)(hbase + (size_t)3 * 16 * NN + ks * 32);

    int m0 = K0 + ks * 32 + q * 8;
    f32x4 sa = *(const f32x4*)&s2r[m0];
    f32x4 sb = *(const f32x4*)&s2r[m0 + 4];
    f32x4 ua = *(const f32x4*)&uu[m0];
    f32x4 ub = *(const f32x4*)&uu[m0 + 4];
    f32x4 va = *(const f32x4*)&vv[m0];
    f32x4 vb = *(const f32x4*)&vv[m0 + 4];
    unsigned wdA = adjT[W0 + ks][c] >> (q * 8);
    unsigned wdB = adjT[W0 + ks][c + 16] >> (q * 8);

    float pA[8], pB[8];
#pragma unroll
    for (int j = 0; j < 4; ++j) {
      float a0 = (sa[j] >= ns1A) ? ArowA * ua[j] : BrowA * va[j];
      float a1 = (sb[j] >= ns1A) ? ArowA * ub[j] : BrowA * vb[j];
      pA[j] = ((wdA >> j) & 1u) ? a0 : 0.f;
      pA[j + 4] = ((wdA >> (j + 4)) & 1u) ? a1 : 0.f;
      float b0 = (sa[j] >= ns1B) ? ArowB * ua[j] : BrowB * va[j];
      float b1 = (sb[j] >= ns1B) ? ArowB * ub[j] : BrowB * vb[j];
      pB[j] = ((wdB >> j) & 1u) ? b0 : 0.f;
      pB[j + 4] = ((wdB >> (j + 4)) & 1u) ? b1 : 0.f;
    }
    LpA += ((pA[0] + pA[1]) + (pA[2] + pA[3])) + ((pA[4] + pA[5]) + (pA[6] + pA[7]));
    LpB += ((pB[0] + pB[1]) + (pB[2] + pB[3])) + ((pB[4] + pB[5]) + (pB[6] + pB[7]));

    union { f16x8 v8; f16x2 h2[4]; } PA, PB;
#pragma unroll
    for (int j = 0; j < 4; ++j) {
      PA.h2[j] = __builtin_bit_cast(f16x2, __builtin_amdgcn_cvt_pkrtz(pA[2 * j], pA[2 * j + 1]));
      PB.h2[j] = __builtin_bit_cast(f16x2, __builtin_amdgcn_cvt_pkrtz(pB[2 * j], pB[2 * j + 1]));
    }

    acc[0][0] = __builtin_amdgcn_mfma_f32_16x16x32_f16(PA.v8, bf0, acc[0][0], 0, 0, 0);
    acc[0][1] = __builtin_amdgcn_mfma_f32_16x16x32_f16(PA.v8, bf1, acc[0][1], 0, 0, 0);
    acc[0][2] = __builtin_amdgcn_mfma_f32_16x16x32_f16(PA.v8, bf2, acc[0][2], 0, 0, 0);
    acc[0][3] = __builtin_amdgcn_mfma_f32_16x16x32_f16(PA.v8, bf3, acc[0][3], 0, 0, 0);
    acc[1][0] = __builtin_amdgcn_mfma_f32_16x16x32_f16(PB.v8, bf0, acc[1][0], 0, 0, 0);
    acc[1][1] = __builtin_amdgcn_mfma_f32_16x16x32_f16(PB.v8, bf1, acc[1][1], 0, 0, 0);
    acc[1][2] = __builtin_amdgcn_mfma_f32_16x16x32_f16(PB.v8, bf2, acc[1][2], 0, 0, 0);
    acc[1][3] = __builtin_amdgcn_mfma_f32_16x16x32_f16(PB.v8, bf3, acc[1][3], 0, 0, 0);
  }

  // ---- epilogue: L + acc cross-wave k-reduction (2-round butterfly) ----
  LpA += __shfl_xor(LpA, 16);
  LpA += __shfl_xor(LpA, 32);
  LpB += __shfl_xor(LpB, 16);
  LpB += __shfl_xor(LpB, 32);
  if (lane < 16) {
    Lbuf[w][c] = LpA;
    Lbuf[w][16 + c] = LpB;
  }
  if (w >= 2) {  // round 1: waves 2,3 publish
#pragma unroll
    for (int t = 0; t < 2; ++t)
#pragma unroll
      for (int d = 0; d < 4; ++d)
        *(f32x4*)&accbuf[w - 2][t][d][lane][0] = acc[t][d];
  }
  __syncthreads();
  if (w < 2) {
#pragma unroll
    for (int t = 0; t < 2; ++t)
#pragma unroll
      for (int d = 0; d < 4; ++d)
        acc[t][d] += *(const f32x4*)&accbuf[w][t][d][lane][0];
  }
  if (tid < 32) {
    float Ls = Lbuf[0][tid] + Lbuf[1][tid] + Lbuf[2][tid] + Lbuf[3][tid];
    invLb[tid] = 1.0f / Ls;
  }
  __syncthreads();
  if (w == 1) {  // round 2: wave 1 publishes
#pragma unroll
    for (int t = 0; t < 2; ++t)
#pragma unroll
      for (int d = 0; d < 4; ++d)
        *(f32x4*)&accbuf[0][t][d][lane][0] = acc[t][d];
  }
  __syncthreads();
  if (w == 0) {
#pragma unroll
    for (int t = 0; t < 2; ++t) {
#pragma unroll
      for (int d = 0; d < 4; ++d)
        acc[t][d] += *(const f32x4*)&accbuf[0][t][d][lane][0];
#pragma unroll
      for (int rr = 0; rr < 4; ++rr) {
        int nloc = t * 16 + q * 4 + rr;
        float il = invLb[nloc];
        size_t o = ((size_t)(b * NN + n0 + nloc)) * FOUT + head * 64;
#pragma unroll
        for (int d = 0; d < 4; ++d) out[o + d * 16 + c] = acc[t][d][rr] * il;
      }
    }
  }
}

extern "C" void kernel_launch(void* const* d_in, const int* in_sizes, int n_in,
                              void* d_out, int out_size, void* d_ws, size_t ws_size,
                              hipStream_t stream) {
  const float* x = (const float*)d_in[0];
  const int* adj = (const int*)d_in[1];
  const float* W = (const float*)d_in[2];
  const float* a = (const float*)d_in[3];
  float* out = (float*)d_out;

  char* ws = (char*)d_ws;
  _Float16* hT = (_Float16*)ws;                              // 4 MB
  _Float16* WT = (_Float16*)(ws + (size_t)4 * 1024 * 1024);  // 128 KB
  float* s1_ws = (float*)(ws + (size_t)4 * 1024 * 1024 + 128 * 1024);
  float* s2_ws = s1_ws + (size_t)BB * H * NN;
  float* u_ws = s2_ws + (size_t)BB * H * NN;
  float* v_ws = u_ws + (size_t)BB * H * NN;
  unsigned* adjP = (unsigned*)(v_ws + (size_t)BB * H * NN);  // 1 MB

  prep<<<1040, 256, 0, stream>>>(adj, adjP, W, WT);
  gemm_xw<<<dim3(128, 4), 256, 0, stream>>>(x, WT, a, hT, s1_ws, s2_ws, u_ws, v_ws);
  attn<<<dim3(32, 32), 256, 0, stream>>>(hT, s1_ws, s2_ws, u_ws, v_ws, adjP, out);
}

// Round 12
// 114.442 us; speedup vs baseline: 1.1411x; 1.0223x over previous
//
#include <hip/hip_runtime.h>
#include <math.h>

#define H 4
#define HD 64
#define NN 1024
#define BB 8
#define FIN 256
#define FOUT 256

typedef _Float16 f16x8 __attribute__((ext_vector_type(8)));
typedef _Float16 f16x4 __attribute__((ext_vector_type(4)));
typedef _Float16 f16x2 __attribute__((ext_vector_type(2)));
typedef float f32x4 __attribute__((ext_vector_type(4)));

// ---------------------------------------------------------------------------
// Kernel 0: prep. Blocks 0..1023: pack adj -> 1 bit/edge (streaming).
// Blocks 1024..1039: WT[f][k] = (fp16) W[k][f] in 64x64 tiles.
// (Pack and WT overlap inside this one kernel; R7/R10 showed fusing pack
//  into gemm's grid regresses.)
// ---------------------------------------------------------------------------
__global__ __launch_bounds__(256) void prep(const int* __restrict__ adj,
                                            unsigned* __restrict__ adjP,
                                            const float* __restrict__ W,
                                            _Float16* __restrict__ WT) {
  __shared__ float tile[64][68];
  const int tid = threadIdx.x;
  if (blockIdx.x < 1024) {
    size_t widx = (size_t)blockIdx.x * 256 + tid;  // [0, 8*1024*32)
    const int4* p = (const int4*)adj + widx * 8;
    int4 v[8];
#pragma unroll
    for (int i = 0; i < 8; ++i) v[i] = p[i];
    unsigned bits = 0;
#pragma unroll
    for (int i = 0; i < 8; ++i) {
      bits |= (v[i].x != 0 ? 1u : 0u) << (4 * i);
      bits |= (v[i].y != 0 ? 2u : 0u) << (4 * i);
      bits |= (v[i].z != 0 ? 4u : 0u) << (4 * i);
      bits |= (v[i].w != 0 ? 8u : 0u) << (4 * i);
    }
    adjP[widx] = bits;
  } else {
    const int bx = blockIdx.x - 1024;
    const int k0 = (bx & 3) * 64, f0 = (bx >> 2) * 64;
    const int r = tid >> 4, c4 = (tid & 15) * 4;
#pragma unroll
    for (int p = 0; p < 4; ++p) {
      float4 v = *(const float4*)&W[(size_t)(k0 + p * 16 + r) * FOUT + f0 + c4];
      *(float4*)&tile[p * 16 + r][c4] = v;
    }
    __syncthreads();
    const int f = tid >> 2, kg = (tid & 3) * 16;
#pragma unroll
    for (int i = 0; i < 4; ++i) {
      f16x4 o;
#pragma unroll
      for (int j = 0; j < 4; ++j) o[j] = (_Float16)tile[kg + i * 4 + j][f];
      *(f16x4*)&WT[(size_t)(f0 + f) * FIN + k0 + kg + i * 4] = o;
    }
  }
}

// ---------------------------------------------------------------------------
// Kernel 1: h = x @ W via fp16 MFMA. Block = 64 rows x 1 head, 512 blocks.
// Two-phase x staging (16 float4 in flight); W B-frags from WT (L2 b128s).
// Epilogue fuses scores: s1, s2, u=exp(s2), v=exp(0.2*s2).
// (R10 showed the LDS-free variant regresses; keep the staged version.)
// ---------------------------------------------------------------------------
__global__ __launch_bounds__(256) void gemm_xw(const float* __restrict__ x,
                                               const _Float16* __restrict__ WT,
                                               const float* __restrict__ a,
                                               _Float16* __restrict__ hT,
                                               float* __restrict__ s1_ws,
                                               float* __restrict__ s2_ws,
                                               float* __restrict__ u_ws,
                                               float* __restrict__ v_ws) {
  __shared__ _Float16 xs[64][264];  // stride 528B
  const int tid = threadIdx.x;
  const int lane = tid & 63, w = tid >> 6;
  const int c = lane & 15, q = lane >> 4;
  const int bn0 = blockIdx.x * 64;
  const int head = blockIdx.y;
  const int b = bn0 >> 10, nb = bn0 & 1023;
  const int bh = b * H + head;

  float4 v[16];
#pragma unroll
  for (int p = 0; p < 16; ++p) {
    int f = p * 256 + tid;  // float4 index in [0, 4096)
    int row = f >> 6, col = (f & 63) * 4;
    v[p] = *(const float4*)&x[(size_t)(bn0 + row) * FIN + col];
  }
#pragma unroll
  for (int p = 0; p < 16; ++p) {
    int f = p * 256 + tid;
    int row = f >> 6, col = (f & 63) * 4;
    f16x4 h4;
    h4[0] = (_Float16)v[p].x; h4[1] = (_Float16)v[p].y;
    h4[2] = (_Float16)v[p].z; h4[3] = (_Float16)v[p].w;
    *(f16x4*)&xs[row][col] = h4;
  }
  __syncthreads();

  f32x4 acc[4];
#pragma unroll
  for (int t = 0; t < 4; ++t) acc[t] = (f32x4){0.f, 0.f, 0.f, 0.f};
  const _Float16* wbase = WT + (size_t)head * 64 * FIN;
#pragma unroll
  for (int ks = 0; ks < 8; ++ks) {
    f16x8 af = *(const f16x8*)&xs[w * 16 + c][ks * 32 + q * 8];
#pragma unroll
    for (int t = 0; t < 4; ++t) {
      f16x8 bf = *(const f16x8*)&wbase[(size_t)(t * 16 + c) * FIN + ks * 32 + q * 8];
      acc[t] = __builtin_amdgcn_mfma_f32_16x16x32_f16(af, bf, acc[t], 0, 0, 0);
    }
  }

  float a1v[4], a2v[4];
#pragma unroll
  for (int t = 0; t < 4; ++t) {
    a1v[t] = a[head * 2 * HD + t * 16 + c];
    a2v[t] = a[head * 2 * HD + HD + t * 16 + c];
  }
  float s1p[4] = {0.f, 0.f, 0.f, 0.f};
  float s2p[4] = {0.f, 0.f, 0.f, 0.f};
#pragma unroll
  for (int t = 0; t < 4; ++t) {
    f16x4 hv;
#pragma unroll
    for (int rr = 0; rr < 4; ++rr) {
      hv[rr] = (_Float16)acc[t][rr];
      s1p[rr] += acc[t][rr] * a1v[t];
      s2p[rr] += acc[t][rr] * a2v[t];
    }
    *(f16x4*)&hT[((size_t)(bh * 64 + t * 16 + c)) * NN + nb + w * 16 + q * 4] = hv;
  }
#pragma unroll
  for (int rr = 0; rr < 4; ++rr) {
    float s1 = s1p[rr], s2 = s2p[rr];
#pragma unroll
    for (int off = 8; off; off >>= 1) {
      s1 += __shfl_xor(s1, off);
      s2 += __shfl_xor(s2, off);
    }
    if (c == 0) {
      int n = nb + w * 16 + q * 4 + rr;
      size_t idx = (size_t)bh * NN + n;
      s1_ws[idx] = s1;
      s2_ws[idx] = s2;
      u_ws[idx] = __expf(s2);
      v_ws[idx] = __expf(0.2f * s2);
    }
  }
}

// ---------------------------------------------------------------------------
// Kernel 2: attention. Block = 32 n-rows x (b,h); 1024 blocks, 4 waves.
// BYTE-IDENTICAL to the 114.5us round-8 version (verified session optimum;
// R11 showed the XCD swizzle regresses slightly — removed).
// Barrier-free in-register A-fragments; unmasked block-max shift (softmax
// normalization cancels any shift >= row max; exact for adj=ones).
// ---------------------------------------------------------------------------
__global__ __launch_bounds__(256) void attn(const _Float16* __restrict__ hT,
                                            const float* __restrict__ s1_ws,
                                            const float* __restrict__ s2_ws,
                                            const float* __restrict__ u_ws,
                                            const float* __restrict__ v_ws,
                                            const unsigned* __restrict__ adjP,
                                            float* __restrict__ out) {
  __shared__ float s2r[NN], uu[NN], vv[NN];   // 12 KB
  __shared__ unsigned adjT[32][32];           // 4 KB, [word][row]
  __shared__ float accbuf[2][2][4][64][4];    // 16 KB reduction buffer
  __shared__ float Mbuf[4];                   // 16 B (block max exchange)
  __shared__ float Lbuf[4][32];               // 512 B
  __shared__ float invLb[32];                 // 128 B
  const int tid = threadIdx.x, lane = tid & 63, w = tid >> 6;
  const int c = lane & 15, q = lane >> 4;
  const int ntile = blockIdx.x, bh = blockIdx.y;
  const int b = bh >> 2, head = bh & 3;
  const int n0 = ntile * 32;
  const int K0 = w * 256, W0 = w * 8;  // this wave's k-quarter

  float4 s2f;
  {
    size_t base = (size_t)bh * NN + tid * 4;
    s2f = *(const float4*)&s2_ws[base];
    *(float4*)&s2r[tid * 4] = s2f;
    *(float4*)&uu[tid * 4] = *(const float4*)&u_ws[base];
    *(float4*)&vv[tid * 4] = *(const float4*)&v_ws[base];
    const int row = tid >> 3, wd0 = (tid & 7) * 4;
    uint4 aw = *(const uint4*)&adjP[((size_t)(b * NN + n0 + row)) * 32 + wd0];
    adjT[wd0 + 0][row] = aw.x;
    adjT[wd0 + 1][row] = aw.y;
    adjT[wd0 + 2][row] = aw.z;
    adjT[wd0 + 3][row] = aw.w;
  }
  // block-wide unmasked max of s2 (register source, no LDS dependency)
  float tmax = fmaxf(fmaxf(s2f.x, s2f.y), fmaxf(s2f.z, s2f.w));
#pragma unroll
  for (int off = 32; off; off >>= 1) tmax = fmaxf(tmax, __shfl_xor(tmax, off));
  if (lane == 0) Mbuf[w] = tmax;
  float s1A = s1_ws[(size_t)bh * NN + n0 + c];       // row c
  float s1B = s1_ws[(size_t)bh * NN + n0 + 16 + c];  // row c+16
  __syncthreads();  // stage visibility + Mbuf

  float mxall = fmaxf(fmaxf(Mbuf[0], Mbuf[1]), fmaxf(Mbuf[2], Mbuf[3]));
  float tA = s1A + mxall, tB = s1B + mxall;
  float MA = fmaxf(tA, 0.2f * tA);  // lrelu (monotone => valid shift)
  float MB = fmaxf(tB, 0.2f * tB);
  float ArowA = __expf(s1A - MA), BrowA = __expf(0.2f * s1A - MA), ns1A = -s1A;
  float ArowB = __expf(s1B - MB), BrowB = __expf(0.2f * s1B - MB), ns1B = -s1B;

  // ---- main loop: barrier-free, in-register A-fragments, k-quarter/wave ----
  float LpA = 0.f, LpB = 0.f;
  f32x4 acc[2][4];
#pragma unroll
  for (int t = 0; t < 2; ++t)
#pragma unroll
    for (int d = 0; d < 4; ++d) acc[t][d] = (f32x4){0.f, 0.f, 0.f, 0.f};
  const _Float16* hbase = hT + (size_t)bh * 64 * NN + (size_t)c * NN + K0 + q * 8;

#pragma unroll 2
  for (int ks = 0; ks < 8; ++ks) {
    // B-frags for this k-slice, all 4 d-blocks (issued before A-build -> the
    // ~160cy of P-gen VALU below hides the L2 latency)
    f16x8 bf0 = *(const f16x8*)(hbase + (size_t)0 * 16 * NN + ks * 32);
    f16x8 bf1 = *(const f16x8*)(hbase + (size_t)1 * 16 * NN + ks * 32);
    f16x8 bf2 = *(const f16x8*)(hbase + (size_t)2 * 16 * NN + ks * 32);
    f16x8 bf3 = *(const f16x8*)(hbase + (size_t)3 * 16 * NN + ks * 32);

    int m0 = K0 + ks * 32 + q * 8;
    f32x4 sa = *(const f32x4*)&s2r[m0];
    f32x4 sb = *(const f32x4*)&s2r[m0 + 4];
    f32x4 ua = *(const f32x4*)&uu[m0];
    f32x4 ub = *(const f32x4*)&uu[m0 + 4];
    f32x4 va = *(const f32x4*)&vv[m0];
    f32x4 vb = *(const f32x4*)&vv[m0 + 4];
    unsigned wdA = adjT[W0 + ks][c] >> (q * 8);
    unsigned wdB = adjT[W0 + ks][c + 16] >> (q * 8);

    float pA[8], pB[8];
#pragma unroll
    for (int j = 0; j < 4; ++j) {
      float a0 = (sa[j] >= ns1A) ? ArowA * ua[j] : BrowA * va[j];
      float a1 = (sb[j] >= ns1A) ? ArowA * ub[j] : BrowA * vb[j];
      pA[j] = ((wdA >> j) & 1u) ? a0 : 0.f;
      pA[j + 4] = ((wdA >> (j + 4)) & 1u) ? a1 : 0.f;
      float b0 = (sa[j] >= ns1B) ? ArowB * ua[j] : BrowB * va[j];
      float b1 = (sb[j] >= ns1B) ? ArowB * ub[j] : BrowB * vb[j];
      pB[j] = ((wdB >> j) & 1u) ? b0 : 0.f;
      pB[j + 4] = ((wdB >> (j + 4)) & 1u) ? b1 : 0.f;
    }
    LpA += ((pA[0] + pA[1]) + (pA[2] + pA[3])) + ((pA[4] + pA[5]) + (pA[6] + pA[7]));
    LpB += ((pB[0] + pB[1]) + (pB[2] + pB[3])) + ((pB[4] + pB[5]) + (pB[6] + pB[7]));

    union { f16x8 v8; f16x2 h2[4]; } PA, PB;
#pragma unroll
    for (int j = 0; j < 4; ++j) {
      PA.h2[j] = __builtin_bit_cast(f16x2, __builtin_amdgcn_cvt_pkrtz(pA[2 * j], pA[2 * j + 1]));
      PB.h2[j] = __builtin_bit_cast(f16x2, __builtin_amdgcn_cvt_pkrtz(pB[2 * j], pB[2 * j + 1]));
    }

    acc[0][0] = __builtin_amdgcn_mfma_f32_16x16x32_f16(PA.v8, bf0, acc[0][0], 0, 0, 0);
    acc[0][1] = __builtin_amdgcn_mfma_f32_16x16x32_f16(PA.v8, bf1, acc[0][1], 0, 0, 0);
    acc[0][2] = __builtin_amdgcn_mfma_f32_16x16x32_f16(PA.v8, bf2, acc[0][2], 0, 0, 0);
    acc[0][3] = __builtin_amdgcn_mfma_f32_16x16x32_f16(PA.v8, bf3, acc[0][3], 0, 0, 0);
    acc[1][0] = __builtin_amdgcn_mfma_f32_16x16x32_f16(PB.v8, bf0, acc[1][0], 0, 0, 0);
    acc[1][1] = __builtin_amdgcn_mfma_f32_16x16x32_f16(PB.v8, bf1, acc[1][1], 0, 0, 0);
    acc[1][2] = __builtin_amdgcn_mfma_f32_16x16x32_f16(PB.v8, bf2, acc[1][2], 0, 0, 0);
    acc[1][3] = __builtin_amdgcn_mfma_f32_16x16x32_f16(PB.v8, bf3, acc[1][3], 0, 0, 0);
  }

  // ---- epilogue: L + acc cross-wave k-reduction (2-round butterfly) ----
  LpA += __shfl_xor(LpA, 16);
  LpA += __shfl_xor(LpA, 32);
  LpB += __shfl_xor(LpB, 16);
  LpB += __shfl_xor(LpB, 32);
  if (lane < 16) {
    Lbuf[w][c] = LpA;
    Lbuf[w][16 + c] = LpB;
  }
  if (w >= 2) {  // round 1: waves 2,3 publish
#pragma unroll
    for (int t = 0; t < 2; ++t)
#pragma unroll
      for (int d = 0; d < 4; ++d)
        *(f32x4*)&accbuf[w - 2][t][d][lane][0] = acc[t][d];
  }
  __syncthreads();
  if (w < 2) {
#pragma unroll
    for (int t = 0; t < 2; ++t)
#pragma unroll
      for (int d = 0; d < 4; ++d)
        acc[t][d] += *(const f32x4*)&accbuf[w][t][d][lane][0];
  }
  if (tid < 32) {
    float Ls = Lbuf[0][tid] + Lbuf[1][tid] + Lbuf[2][tid] + Lbuf[3][tid];
    invLb[tid] = 1.0f / Ls;
  }
  __syncthreads();
  if (w == 1) {  // round 2: wave 1 publishes
#pragma unroll
    for (int t = 0; t < 2; ++t)
#pragma unroll
      for (int d = 0; d < 4; ++d)
        *(f32x4*)&accbuf[0][t][d][lane][0] = acc[t][d];
  }
  __syncthreads();
  if (w == 0) {
#pragma unroll
    for (int t = 0; t < 2; ++t) {
#pragma unroll
      for (int d = 0; d < 4; ++d)
        acc[t][d] += *(const f32x4*)&accbuf[0][t][d][lane][0];
#pragma unroll
      for (int rr = 0; rr < 4; ++rr) {
        int nloc = t * 16 + q * 4 + rr;
        float il = invLb[nloc];
        size_t o = ((size_t)(b * NN + n0 + nloc)) * FOUT + head * 64;
#pragma unroll
        for (int d = 0; d < 4; ++d) out[o + d * 16 + c] = acc[t][d][rr] * il;
      }
    }
  }
}

extern "C" void kernel_launch(void* const* d_in, const int* in_sizes, int n_in,
                              void* d_out, int out_size, void* d_ws, size_t ws_size,
                              hipStream_t stream) {
  const float* x = (const float*)d_in[0];
  const int* adj = (const int*)d_in[1];
  const float* W = (const float*)d_in[2];
  const float* a = (const float*)d_in[3];
  float* out = (float*)d_out;

  char* ws = (char*)d_ws;
  _Float16* hT = (_Float16*)ws;                              // 4 MB
  _Float16* WT = (_Float16*)(ws + (size_t)4 * 1024 * 1024);  // 128 KB
  float* s1_ws = (float*)(ws + (size_t)4 * 1024 * 1024 + 128 * 1024);
  float* s2_ws = s1_ws + (size_t)BB * H * NN;
  float* u_ws = s2_ws + (size_t)BB * H * NN;
  float* v_ws = u_ws + (size_t)BB * H * NN;
  unsigned* adjP = (unsigned*)(v_ws + (size_t)BB * H * NN);  // 1 MB

  prep<<<1040, 256, 0, stream>>>(adj, adjP, W, WT);
  gemm_xw<<<dim3(128, 4), 256, 0, stream>>>(x, WT, a, hT, s1_ws, s2_ws, u_ws, v_ws);
  attn<<<dim3(32, 32), 256, 0, stream>>>(hT, s1_ws, s2_ws, u_ws, v_ws, adjP, out);
}